// Round 1
// baseline (391.831 us; speedup 1.0000x reference)
//
#include <hip/hip_runtime.h>
#include <cstddef>

// Problem constants (X: [128, 256, 32, 32] fp32, groups of 64 channels)
namespace {
constexpr int NB   = 128;          // batch
constexpr int NCH  = 256;          // channels
constexpr int SPA  = 1024;         // 32*32 spatial
constexpr int NG   = 4;            // groups
constexpr int NCC  = 64;           // channels per group
constexpr int MT   = NB * SPA;     // m = 131072
constexpr float EPSV = 1e-5f;
}

// ---------------------------------------------------------------------------
// Kernel 1: per-(b,g) partial Gram [64x64] and channel sums [64].
// Grid: 512 blocks (bg = g*128 + b), 256 threads.
// LDS tile Xt[64ch][64s] pitch 68 floats; thread computes strided 4x4 Gram tile
// rows d = v+16i, cols e = u+16j  (v=t/16, u=t%16) -> all LDS reads <=2-way.
// ---------------------------------------------------------------------------
__global__ __launch_bounds__(256) void zca_stats(const float* __restrict__ X,
                                                 float* __restrict__ Gpart,
                                                 float* __restrict__ Spart) {
    const int bg = blockIdx.x;
    const int g  = bg >> 7;      // /128
    const int b  = bg & 127;
    const int t  = threadIdx.x;
    const int v  = t >> 4;       // 0..15
    const int u  = t & 15;       // 0..15

    __shared__ float Xt[64][68];

    const float* xb = X + ((size_t)b * NCH + (size_t)g * NCC) * SPA; // [64][1024]

    float acc[4][4];
#pragma unroll
    for (int i = 0; i < 4; ++i)
#pragma unroll
        for (int j = 0; j < 4; ++j) acc[i][j] = 0.f;
    float asum[4] = {0.f, 0.f, 0.f, 0.f};

    for (int st = 0; st < SPA; st += 64) {
        __syncthreads();   // protect Xt from previous iteration's readers
#pragma unroll
        for (int i = 0; i < 4; ++i) {
            int linear = i * 256 + t;          // 0..1023
            int ch = linear >> 4;
            int s4 = linear & 15;
            *reinterpret_cast<float4*>(&Xt[ch][s4 * 4]) =
                *reinterpret_cast<const float4*>(xb + (size_t)ch * SPA + st + s4 * 4);
        }
        __syncthreads();
#pragma unroll
        for (int ss = 0; ss < 64; ss += 4) {
            float4 a4[4], b4[4];
#pragma unroll
            for (int i = 0; i < 4; ++i)
                a4[i] = *reinterpret_cast<const float4*>(&Xt[v + 16 * i][ss]);
#pragma unroll
            for (int j = 0; j < 4; ++j)
                b4[j] = *reinterpret_cast<const float4*>(&Xt[u + 16 * j][ss]);
#pragma unroll
            for (int i = 0; i < 4; ++i) {
                const float ax = a4[i].x, ay = a4[i].y, az = a4[i].z, aw = a4[i].w;
#pragma unroll
                for (int j = 0; j < 4; ++j) {
                    acc[i][j] += ax * b4[j].x + ay * b4[j].y + az * b4[j].z + aw * b4[j].w;
                }
            }
            if (u == 0) {
#pragma unroll
                for (int i = 0; i < 4; ++i)
                    asum[i] += a4[i].x + a4[i].y + a4[i].z + a4[i].w;
            }
        }
    }

    float* Gp = Gpart + (size_t)bg * (NCC * NCC);
#pragma unroll
    for (int i = 0; i < 4; ++i)
#pragma unroll
        for (int j = 0; j < 4; ++j)
            Gp[(v + 16 * i) * NCC + (u + 16 * j)] = acc[i][j];
    if (u == 0) {
        float* Sp = Spart + (size_t)bg * NCC;
#pragma unroll
        for (int i = 0; i < 4; ++i) Sp[v + 16 * i] = asum[i];
    }
}

// ---------------------------------------------------------------------------
// Kernel 2: per-group reduce partials -> Sigma -> rTr -> 5 Newton-Schulz
// iterations -> whitening matrix (weight/bias folded). Grid: 4 blocks, 256 thr.
// P3*Sn computed as P*(P*(P*Sn)) so one LDS temp suffices (register staging).
// ---------------------------------------------------------------------------
__global__ __launch_bounds__(256) void zca_newton(const float* __restrict__ Gpart,
                                                  const float* __restrict__ Spart,
                                                  const float* __restrict__ weight,
                                                  const float* __restrict__ bias,
                                                  float* __restrict__ wmT,
                                                  float* __restrict__ betaOut) {
    const int g = blockIdx.x;
    const int t = threadIdx.x;
    const int v = t >> 4;
    const int u = t & 15;

    __shared__ float Pm[64 * 65];
    __shared__ float Sn[64 * 65];
    __shared__ float Ta[64 * 65];
    __shared__ float meanS[64];
    __shared__ float scal[2];   // rTr, sqrt(rTr)

    // ---- Phase A: reduce Gram partials over the 128 batch-blocks ----
    float accv[16];
#pragma unroll
    for (int i = 0; i < 16; ++i) accv[i] = 0.f;
    const float* Gbase = Gpart + (size_t)g * 128 * 4096;
    for (int b = 0; b < 128; ++b) {
        const float* Gp = Gbase + (size_t)b * 4096;
#pragma unroll
        for (int i = 0; i < 16; ++i) accv[i] += Gp[i * 256 + t];
    }
    if (t < 64) {
        float s = 0.f;
        const float* Sp = Spart + (size_t)g * 128 * 64;
        for (int b = 0; b < 128; ++b) s += Sp[b * 64 + t];
        meanS[t] = s * (1.0f / MT);
    }
    __syncthreads();

    // Sigma (unscaled) into Sn
#pragma unroll
    for (int i = 0; i < 16; ++i) {
        int idx = i * 256 + t;
        int d = idx >> 6, e = idx & 63;
        float sig = accv[i] * (1.0f / MT) - meanS[d] * meanS[e] + (d == e ? EPSV : 0.f);
        Sn[d * 65 + e] = sig;
    }
    __syncthreads();

    if (t < 64) {
        float tr = Sn[t * 65 + t];
        for (int off = 32; off > 0; off >>= 1) tr += __shfl_down(tr, off, 64);
        if (t == 0) {
            scal[0] = 1.0f / tr;
            scal[1] = sqrtf(1.0f / tr);
        }
    }
    __syncthreads();
    const float rTr = scal[0];

    // scale Sn, init P = I
#pragma unroll
    for (int i = 0; i < 16; ++i) {
        int idx = i * 256 + t;
        int d = idx >> 6, e = idx & 63;
        Sn[d * 65 + e] *= rTr;
        Pm[d * 65 + e] = (d == e) ? 1.f : 0.f;
    }
    __syncthreads();

    // 16-element tile matmul: r = (A*B)[rows v+16i][cols u+16j]
    auto mm = [&](const float* A, const float* Bm, float* r) {
#pragma unroll
        for (int q = 0; q < 16; ++q) r[q] = 0.f;
        for (int k = 0; k < 64; ++k) {
            float a[4], bb[4];
#pragma unroll
            for (int i = 0; i < 4; ++i) a[i] = A[(v + 16 * i) * 65 + k];
#pragma unroll
            for (int j = 0; j < 4; ++j) bb[j] = Bm[k * 65 + (u + 16 * j)];
#pragma unroll
            for (int i = 0; i < 4; ++i)
#pragma unroll
                for (int j = 0; j < 4; ++j) r[i * 4 + j] += a[i] * bb[j];
        }
    };
    auto storeTa = [&](const float* r) {
#pragma unroll
        for (int q = 0; q < 16; ++q)
            Ta[(v + 16 * (q >> 2)) * 65 + (u + 16 * (q & 3))] = r[q];
    };

    for (int it = 0; it < 5; ++it) {
        float r[16];
        mm(Pm, Sn, r);      // P*Sn
        storeTa(r);         // Ta not read by anyone since last barrier
        __syncthreads();
        mm(Pm, Ta, r);      // P^2*Sn
        __syncthreads();    // all reads of Ta done
        storeTa(r);
        __syncthreads();
        mm(Pm, Ta, r);      // P^3*Sn
        __syncthreads();    // all reads of Pm done
#pragma unroll
        for (int q = 0; q < 16; ++q) {
            int rr = v + 16 * (q >> 2);
            int cc = u + 16 * (q & 3);
            Pm[rr * 65 + cc] = 1.5f * Pm[rr * 65 + cc] - 0.5f * r[q];
        }
        __syncthreads();
    }

    // Epilogue: wm = P*sqrt(rTr); fold weight; store transposed [k=e][d].
    const float srTr = scal[1];
#pragma unroll
    for (int i = 0; i < 16; ++i) {
        int idx = i * 256 + t;
        int d = idx >> 6, e = idx & 63;
        float wv = weight[g * NCC + d];
        wmT[(size_t)g * 4096 + e * 64 + d] = Pm[d * 65 + e] * srTr * wv;
    }
    if (t < 64) {
        int d = t;
        float s = 0.f;
        for (int e = 0; e < 64; ++e) s += Pm[d * 65 + e] * meanS[e];
        betaOut[g * NCC + d] = bias[g * NCC + d] - weight[g * NCC + d] * srTr * s;
    }
}

// ---------------------------------------------------------------------------
// Kernel 3: out[b][g*64+d][s] = sum_e Wt[e][d]*X[b][g*64+e][s] + beta[d]
// Grid: 512 blocks (bg = g*128 + b), 256 threads. Wt cached in LDS.
// Thread computes contiguous 4x4 (d0 = 4*(t/16), s0 = 4*(t%16)) via float4.
// ---------------------------------------------------------------------------
__global__ __launch_bounds__(256) void zca_apply(const float* __restrict__ X,
                                                 const float* __restrict__ wmT,
                                                 const float* __restrict__ beta,
                                                 float* __restrict__ out) {
    const int bg = blockIdx.x;
    const int g  = bg >> 7;
    const int b  = bg & 127;
    const int t  = threadIdx.x;
    const int d0 = (t >> 4) * 4;
    const int s0 = (t & 15) * 4;

    __shared__ float Wt[64 * 64];   // [k(=e)][d], pitch 64
    __shared__ float Xt[64][68];    // [e][s], pitch 68
    __shared__ float bl[64];

#pragma unroll
    for (int i = 0; i < 16; ++i) Wt[i * 256 + t] = wmT[(size_t)g * 4096 + i * 256 + t];
    if (t < 64) bl[t] = beta[g * NCC + t];

    const float* xb = X + ((size_t)b * NCH + (size_t)g * NCC) * SPA;
    float* ob = out + ((size_t)b * NCH + (size_t)g * NCC) * SPA;

    for (int st = 0; st < SPA; st += 64) {
        __syncthreads();   // Wt/bl visible (first iter); Xt readers done (later iters)
#pragma unroll
        for (int i = 0; i < 4; ++i) {
            int linear = i * 256 + t;
            int ch = linear >> 4;
            int s4 = linear & 15;
            *reinterpret_cast<float4*>(&Xt[ch][s4 * 4]) =
                *reinterpret_cast<const float4*>(xb + (size_t)ch * SPA + st + s4 * 4);
        }
        __syncthreads();

        float acc[4][4];
#pragma unroll
        for (int i = 0; i < 4; ++i)
#pragma unroll
            for (int j = 0; j < 4; ++j) acc[i][j] = 0.f;

        for (int k = 0; k < 64; ++k) {
            const float4 a  = *reinterpret_cast<const float4*>(&Wt[k * 64 + d0]);
            const float4 x4 = *reinterpret_cast<const float4*>(&Xt[k][s0]);
            const float av[4] = {a.x, a.y, a.z, a.w};
            const float xv[4] = {x4.x, x4.y, x4.z, x4.w};
#pragma unroll
            for (int i = 0; i < 4; ++i)
#pragma unroll
                for (int j = 0; j < 4; ++j) acc[i][j] += av[i] * xv[j];
        }

#pragma unroll
        for (int i = 0; i < 4; ++i) {
            float4 o;
            const float be = bl[d0 + i];
            o.x = acc[i][0] + be;
            o.y = acc[i][1] + be;
            o.z = acc[i][2] + be;
            o.w = acc[i][3] + be;
            *reinterpret_cast<float4*>(ob + (size_t)(d0 + i) * SPA + st + s0) = o;
        }
    }
}

// ---------------------------------------------------------------------------
extern "C" void kernel_launch(void* const* d_in, const int* in_sizes, int n_in,
                              void* d_out, int out_size, void* d_ws, size_t ws_size,
                              hipStream_t stream) {
    const float* X      = (const float*)d_in[0];
    const float* weight = (const float*)d_in[1];
    const float* bias   = (const float*)d_in[2];
    float* out = (float*)d_out;

    // ws layout (floats): Gpart[512][4096] | Spart[512][64] | wmT[4][4096] | beta[4][64]
    float* ws    = (float*)d_ws;
    float* Gpart = ws;
    float* Spart = Gpart + (size_t)512 * 4096;
    float* wmT   = Spart + (size_t)512 * 64;
    float* betaW = wmT + (size_t)4 * 4096;
    // total ~8.2 MB of workspace used

    zca_stats<<<dim3(512), dim3(256), 0, stream>>>(X, Gpart, Spart);
    zca_newton<<<dim3(4), dim3(256), 0, stream>>>(Gpart, Spart, weight, bias, wmT, betaW);
    zca_apply<<<dim3(512), dim3(256), 0, stream>>>(X, wmT, betaW, out);
}

// Round 3
// 158.452 us; speedup vs baseline: 2.4729x; 2.4729x over previous
//
#include <hip/hip_runtime.h>
#include <cstddef>
#include <cstdint>

typedef __attribute__((ext_vector_type(8))) short s16x8;   // bf16 A/B frag
typedef __attribute__((ext_vector_type(4))) float f32x4;   // MFMA acc

namespace {
constexpr int NB   = 128;
constexpr int NCH  = 256;
constexpr int SPA  = 1024;
constexpr int NCC  = 64;
constexpr int MT   = NB * SPA;     // 131072
constexpr float EPSV = 1e-5f;
}

__device__ inline unsigned short f2bf(float f) {
    union { float f; unsigned u; } v; v.f = f;
    unsigned r = v.u + 0x7fffu + ((v.u >> 16) & 1u);   // RNE
    return (unsigned short)(r >> 16);
}

__device__ inline s16x8 cvt8(float4 a, float4 b) {
    s16x8 r;
    r[0] = (short)f2bf(a.x); r[1] = (short)f2bf(a.y);
    r[2] = (short)f2bf(a.z); r[3] = (short)f2bf(a.w);
    r[4] = (short)f2bf(b.x); r[5] = (short)f2bf(b.y);
    r[6] = (short)f2bf(b.z); r[7] = (short)f2bf(b.w);
    return r;
}

// ---------------------------------------------------------------------------
// Kernel 1: per-(g,b) partial Gram via bf16 MFMA + channel sums.
// bid = g*128 + b. 4 waves, wave w owns m in [w*256, w*256+256).
// Frag: lane l holds X[cb*16 + (l&15)][k0 + (l>>4)*8 + j], j=0..7 (bf16).
// Same registers serve as A (rows d) and B (cols e) of X·X^T — any k-mapping
// uncertainty cancels; C/D swap would write G^T = G. Layout-robust.
// ---------------------------------------------------------------------------
__global__ __launch_bounds__(256) void zca_stats(const float* __restrict__ X,
                                                 float* __restrict__ Gpart,
                                                 float* __restrict__ Spart) {
    const int bid = blockIdx.x;
    const int g = bid >> 7, b = bid & 127;
    const int t = threadIdx.x;
    const int w = t >> 6, l = t & 63;
    const int lr = l & 15, gq = l >> 4;

    const float* xs = X + ((size_t)b * NCH + (size_t)g * NCC) * SPA;

    f32x4 acc[4][4];
#pragma unroll
    for (int i = 0; i < 4; ++i)
#pragma unroll
        for (int j = 0; j < 4; ++j) acc[i][j] = (f32x4){0.f, 0.f, 0.f, 0.f};
    float csum[4] = {0.f, 0.f, 0.f, 0.f};

    for (int ks = 0; ks < 8; ++ks) {
        const int k0 = w * 256 + ks * 32 + gq * 8;
        s16x8 frag[4];
#pragma unroll
        for (int cb = 0; cb < 4; ++cb) {
            const float* p = xs + (size_t)(cb * 16 + lr) * SPA + k0;
            float4 f0 = *reinterpret_cast<const float4*>(p);
            float4 f1 = *reinterpret_cast<const float4*>(p + 4);
            csum[cb] += (f0.x + f0.y) + (f0.z + f0.w) + (f1.x + f1.y) + (f1.z + f1.w);
            frag[cb] = cvt8(f0, f1);
        }
#pragma unroll
        for (int i = 0; i < 4; ++i)
#pragma unroll
            for (int j = 0; j < 4; ++j)
                acc[i][j] = __builtin_amdgcn_mfma_f32_16x16x32_bf16(frag[i], frag[j], acc[i][j], 0, 0, 0);
    }

    __shared__ float Gl[64 * 66];
    __shared__ float Ssl[4][64];

    // channel sums: reduce over the 4 k-subgroups (lanes l, l^16, l^32, l^48)
#pragma unroll
    for (int cb = 0; cb < 4; ++cb) {
        float s = csum[cb];
        s += __shfl_xor(s, 16, 64);
        s += __shfl_xor(s, 32, 64);
        if (gq == 0) Ssl[w][cb * 16 + lr] = s;
    }

    // Gram: serialized per-wave accumulate into LDS (fixed order -> deterministic)
    for (int ww = 0; ww < 4; ++ww) {
        if (w == ww) {
#pragma unroll
            for (int i = 0; i < 4; ++i)
#pragma unroll
                for (int j = 0; j < 4; ++j)
#pragma unroll
                    for (int q = 0; q < 4; ++q) {
                        const int d = i * 16 + gq * 4 + q;
                        const int e = j * 16 + lr;
                        if (ww == 0) Gl[d * 66 + e] = acc[i][j][q];
                        else         Gl[d * 66 + e] += acc[i][j][q];
                    }
        }
        __syncthreads();
    }

#pragma unroll
    for (int i = 0; i < 16; ++i) {
        const int idx = i * 256 + t;
        const int d = idx >> 6, e = idx & 63;
        Gpart[(size_t)bid * 4096 + idx] = Gl[d * 66 + e];
    }
    if (t < 64)
        Spart[(size_t)bid * 64 + t] = ((Ssl[0][t] + Ssl[1][t]) + (Ssl[2][t] + Ssl[3][t]));
}

// ---------------------------------------------------------------------------
// Kernel 2: reduce 128 partials/group -> Gram sums; sub-reduce channel sums.
// Grid 64 = 4 groups x 16 element-blocks, 256 threads.
// ---------------------------------------------------------------------------
__global__ __launch_bounds__(256) void zca_reduce(const float* __restrict__ Gpart,
                                                  const float* __restrict__ Spart,
                                                  float* __restrict__ Gsum,
                                                  float* __restrict__ Ssub) {
    const int g = blockIdx.x >> 4, eb = blockIdx.x & 15;
    const int t = threadIdx.x;
    const float* p = Gpart + (size_t)g * 128 * 4096 + eb * 256 + t;
    float a0 = 0.f, a1 = 0.f, a2 = 0.f, a3 = 0.f;
    for (int q = 0; q < 128; q += 4) {
        a0 += p[(size_t)(q + 0) * 4096];
        a1 += p[(size_t)(q + 1) * 4096];
        a2 += p[(size_t)(q + 2) * 4096];
        a3 += p[(size_t)(q + 3) * 4096];
    }
    Gsum[(size_t)g * 4096 + eb * 256 + t] = (a0 + a1) + (a2 + a3);

    if (t < 64) {
        float s = 0.f;
        for (int q = 0; q < 8; ++q)
            s += Spart[(size_t)(g * 128 + eb * 8 + q) * 64 + t];
        Ssub[(size_t)(g * 16 + eb) * 64 + t] = s;
    }
}

// ---------------------------------------------------------------------------
// Kernel 3 (round-1 proven body): Sigma -> rTr -> 5 Newton-Schulz -> fp32 wmT
// (transposed [e][d], weight folded) + folded bias. Grid 4, 256 threads.
// Only Phase A changed: reads pre-reduced Gsum/Ssub instead of raw partials.
// ---------------------------------------------------------------------------
__global__ __launch_bounds__(256) void zca_newton(const float* __restrict__ Gsum,
                                                  const float* __restrict__ Ssub,
                                                  const float* __restrict__ weight,
                                                  const float* __restrict__ bias,
                                                  float* __restrict__ wmT,
                                                  float* __restrict__ betaOut) {
    const int g = blockIdx.x;
    const int t = threadIdx.x;
    const int v = t >> 4;
    const int u = t & 15;

    __shared__ float Pm[64 * 65];
    __shared__ float Sn[64 * 65];
    __shared__ float Ta[64 * 65];
    __shared__ float meanS[64];
    __shared__ float scal[2];   // rTr, sqrt(rTr)

    if (t < 64) {
        float s = 0.f;
        for (int eb = 0; eb < 16; ++eb) s += Ssub[(size_t)(g * 16 + eb) * 64 + t];
        meanS[t] = s * (1.0f / MT);
    }
    __syncthreads();

    // Sigma (with eps) into Sn
#pragma unroll
    for (int i = 0; i < 16; ++i) {
        int idx = i * 256 + t;
        int d = idx >> 6, e = idx & 63;
        float sig = Gsum[(size_t)g * 4096 + idx] * (1.0f / MT)
                    - meanS[d] * meanS[e] + (d == e ? EPSV : 0.f);
        Sn[d * 65 + e] = sig;
    }
    __syncthreads();

    if (t < 64) {
        float tr = Sn[t * 65 + t];
        for (int off = 32; off > 0; off >>= 1) tr += __shfl_down(tr, off, 64);
        if (t == 0) {
            scal[0] = 1.0f / tr;
            scal[1] = sqrtf(1.0f / tr);
        }
    }
    __syncthreads();
    const float rTr = scal[0];

    // scale Sn, init P = I
#pragma unroll
    for (int i = 0; i < 16; ++i) {
        int idx = i * 256 + t;
        int d = idx >> 6, e = idx & 63;
        Sn[d * 65 + e] *= rTr;
        Pm[d * 65 + e] = (d == e) ? 1.f : 0.f;
    }
    __syncthreads();

    // 16-element tile matmul: r = (A*B)[rows v+16i][cols u+16j]
    auto mm = [&](const float* A, const float* Bm, float* r) {
#pragma unroll
        for (int q = 0; q < 16; ++q) r[q] = 0.f;
        for (int k = 0; k < 64; ++k) {
            float a[4], bb[4];
#pragma unroll
            for (int i = 0; i < 4; ++i) a[i] = A[(v + 16 * i) * 65 + k];
#pragma unroll
            for (int j = 0; j < 4; ++j) bb[j] = Bm[k * 65 + (u + 16 * j)];
#pragma unroll
            for (int i = 0; i < 4; ++i)
#pragma unroll
                for (int j = 0; j < 4; ++j) r[i * 4 + j] += a[i] * bb[j];
        }
    };
    auto storeTa = [&](const float* r) {
#pragma unroll
        for (int q = 0; q < 16; ++q)
            Ta[(v + 16 * (q >> 2)) * 65 + (u + 16 * (q & 3))] = r[q];
    };

    for (int it = 0; it < 5; ++it) {
        float r[16];
        mm(Pm, Sn, r);      // P*Sn
        storeTa(r);         // Ta not read by anyone since last barrier
        __syncthreads();
        mm(Pm, Ta, r);      // P^2*Sn
        __syncthreads();    // all reads of Ta done
        storeTa(r);
        __syncthreads();
        mm(Pm, Ta, r);      // P^3*Sn
        __syncthreads();    // all reads of Pm done
#pragma unroll
        for (int q = 0; q < 16; ++q) {
            int rr = v + 16 * (q >> 2);
            int cc = u + 16 * (q & 3);
            Pm[rr * 65 + cc] = 1.5f * Pm[rr * 65 + cc] - 0.5f * r[q];
        }
        __syncthreads();
    }

    // Epilogue: wm = P*sqrt(rTr); fold weight; store transposed [k=e][d].
    const float srTr = scal[1];
#pragma unroll
    for (int i = 0; i < 16; ++i) {
        int idx = i * 256 + t;
        int d = idx >> 6, e = idx & 63;
        float wv = weight[g * NCC + d];
        wmT[(size_t)g * 4096 + e * 64 + d] = Pm[d * 65 + e] * srTr * wv;
    }
    if (t < 64) {
        int d = t;
        float s = 0.f;
        for (int e = 0; e < 64; ++e) s += Pm[d * 65 + e] * meanS[e];
        betaOut[g * NCC + d] = bias[g * NCC + d] - weight[g * NCC + d] * srTr * s;
    }
}

// ---------------------------------------------------------------------------
// Kernel 4 (round-1 proven, verbatim): out[b][g*64+d][s] =
//   sum_e Wt[e][d]*X[b][g*64+e][s] + beta[d].  Grid 512, 256 threads.
// ---------------------------------------------------------------------------
__global__ __launch_bounds__(256) void zca_apply(const float* __restrict__ X,
                                                 const float* __restrict__ wmT,
                                                 const float* __restrict__ beta,
                                                 float* __restrict__ out) {
    const int bg = blockIdx.x;
    const int g  = bg >> 7;
    const int b  = bg & 127;
    const int t  = threadIdx.x;
    const int d0 = (t >> 4) * 4;
    const int s0 = (t & 15) * 4;

    __shared__ float Wt[64 * 64];   // [k(=e)][d], pitch 64
    __shared__ float Xt[64][68];    // [e][s], pitch 68
    __shared__ float bl[64];

#pragma unroll
    for (int i = 0; i < 16; ++i) Wt[i * 256 + t] = wmT[(size_t)g * 4096 + i * 256 + t];
    if (t < 64) bl[t] = beta[g * NCC + t];

    const float* xb = X + ((size_t)b * NCH + (size_t)g * NCC) * SPA;
    float* ob = out + ((size_t)b * NCH + (size_t)g * NCC) * SPA;

    for (int st = 0; st < SPA; st += 64) {
        __syncthreads();   // Wt/bl visible (first iter); Xt readers done (later iters)
#pragma unroll
        for (int i = 0; i < 4; ++i) {
            int linear = i * 256 + t;
            int ch = linear >> 4;
            int s4 = linear & 15;
            *reinterpret_cast<float4*>(&Xt[ch][s4 * 4]) =
                *reinterpret_cast<const float4*>(xb + (size_t)ch * SPA + st + s4 * 4);
        }
        __syncthreads();

        float acc[4][4];
#pragma unroll
        for (int i = 0; i < 4; ++i)
#pragma unroll
            for (int j = 0; j < 4; ++j) acc[i][j] = 0.f;

        for (int k = 0; k < 64; ++k) {
            const float4 a  = *reinterpret_cast<const float4*>(&Wt[k * 64 + d0]);
            const float4 x4 = *reinterpret_cast<const float4*>(&Xt[k][s0]);
            const float av[4] = {a.x, a.y, a.z, a.w};
            const float xv[4] = {x4.x, x4.y, x4.z, x4.w};
#pragma unroll
            for (int i = 0; i < 4; ++i)
#pragma unroll
                for (int j = 0; j < 4; ++j) acc[i][j] += av[i] * xv[j];
        }

#pragma unroll
        for (int i = 0; i < 4; ++i) {
            float4 o;
            const float be = bl[d0 + i];
            o.x = acc[i][0] + be;
            o.y = acc[i][1] + be;
            o.z = acc[i][2] + be;
            o.w = acc[i][3] + be;
            *reinterpret_cast<float4*>(ob + (size_t)(d0 + i) * SPA + st + s0) = o;
        }
    }
}

// ---------------------------------------------------------------------------
extern "C" void kernel_launch(void* const* d_in, const int* in_sizes, int n_in,
                              void* d_out, int out_size, void* d_ws, size_t ws_size,
                              hipStream_t stream) {
    const float* X      = (const float*)d_in[0];
    const float* weight = (const float*)d_in[1];
    const float* bias   = (const float*)d_in[2];
    float* out = (float*)d_out;

    // ws layout (floats): Gpart[512*4096] | Spart[512*64] | Gsum[4*4096] |
    //                     Ssub[4*16*64] | wmT[4*4096] | beta[256]   (~8.7 MB)
    float* ws    = (float*)d_ws;
    float* Gpart = ws;
    float* Spart = Gpart + (size_t)512 * 4096;
    float* Gsum  = Spart + (size_t)512 * 64;
    float* Ssub  = Gsum + (size_t)4 * 4096;
    float* wmT   = Ssub + (size_t)4 * 16 * 64;
    float* betaW = wmT + (size_t)4 * 4096;

    zca_stats <<<dim3(512), dim3(256), 0, stream>>>(X, Gpart, Spart);
    zca_reduce<<<dim3(64),  dim3(256), 0, stream>>>(Gpart, Spart, Gsum, Ssub);
    zca_newton<<<dim3(4),   dim3(256), 0, stream>>>(Gsum, Ssub, weight, bias, wmT, betaW);
    zca_apply <<<dim3(512), dim3(256), 0, stream>>>(X, wmT, betaW, out);
}

// Round 4
// 145.052 us; speedup vs baseline: 2.7013x; 1.0924x over previous
//
#include <hip/hip_runtime.h>
#include <hip/hip_bf16.h>
#include <cstddef>
#include <cstdint>

typedef __attribute__((ext_vector_type(8))) short s16x8;   // bf16 A/B frag
typedef __attribute__((ext_vector_type(4))) float f32x4;   // MFMA acc

namespace {
constexpr int NB   = 128;
constexpr int NCH  = 256;
constexpr int SPA  = 1024;
constexpr int NCC  = 64;
constexpr int MT   = NB * SPA;     // 131072
constexpr float EPSV = 1e-5f;
}

__device__ inline unsigned short f2bf(float f) {
    union { float f; unsigned u; } v; v.f = f;
    unsigned r = v.u + 0x7fffu + ((v.u >> 16) & 1u);   // RNE
    return (unsigned short)(r >> 16);
}

// 8 floats -> 8 bf16 via v_cvt_pk_bf16_f32 pairs (RNE, matches f2bf)
__device__ inline s16x8 cvt8(float4 a, float4 b) {
    union { __hip_bfloat162 h[4]; s16x8 s; } u;
    u.h[0] = __float22bfloat162_rn(make_float2(a.x, a.y));
    u.h[1] = __float22bfloat162_rn(make_float2(a.z, a.w));
    u.h[2] = __float22bfloat162_rn(make_float2(b.x, b.y));
    u.h[3] = __float22bfloat162_rn(make_float2(b.z, b.w));
    return u.s;
}

__device__ inline s16x8 pack8(const float* v) {
    union { __hip_bfloat162 h[4]; s16x8 s; } u;
    u.h[0] = __float22bfloat162_rn(make_float2(v[0], v[1]));
    u.h[1] = __float22bfloat162_rn(make_float2(v[2], v[3]));
    u.h[2] = __float22bfloat162_rn(make_float2(v[4], v[5]));
    u.h[3] = __float22bfloat162_rn(make_float2(v[6], v[7]));
    return u.s;
}

// ---------------------------------------------------------------------------
// Kernel 1: per-(g,b) partial Gram via bf16 MFMA + channel sums.
// (round-3 proven; only cvt8 internals changed to cvt_pk)
// ---------------------------------------------------------------------------
__global__ __launch_bounds__(256) void zca_stats(const float* __restrict__ X,
                                                 float* __restrict__ Gpart,
                                                 float* __restrict__ Spart) {
    const int bid = blockIdx.x;
    const int g = bid >> 7, b = bid & 127;
    const int t = threadIdx.x;
    const int w = t >> 6, l = t & 63;
    const int lr = l & 15, gq = l >> 4;

    const float* xs = X + ((size_t)b * NCH + (size_t)g * NCC) * SPA;

    f32x4 acc[4][4];
#pragma unroll
    for (int i = 0; i < 4; ++i)
#pragma unroll
        for (int j = 0; j < 4; ++j) acc[i][j] = (f32x4){0.f, 0.f, 0.f, 0.f};
    float csum[4] = {0.f, 0.f, 0.f, 0.f};

    for (int ks = 0; ks < 8; ++ks) {
        const int k0 = w * 256 + ks * 32 + gq * 8;
        s16x8 frag[4];
#pragma unroll
        for (int cb = 0; cb < 4; ++cb) {
            const float* p = xs + (size_t)(cb * 16 + lr) * SPA + k0;
            float4 f0 = *reinterpret_cast<const float4*>(p);
            float4 f1 = *reinterpret_cast<const float4*>(p + 4);
            csum[cb] += (f0.x + f0.y) + (f0.z + f0.w) + (f1.x + f1.y) + (f1.z + f1.w);
            frag[cb] = cvt8(f0, f1);
        }
#pragma unroll
        for (int i = 0; i < 4; ++i)
#pragma unroll
            for (int j = 0; j < 4; ++j)
                acc[i][j] = __builtin_amdgcn_mfma_f32_16x16x32_bf16(frag[i], frag[j], acc[i][j], 0, 0, 0);
    }

    __shared__ float Gl[64 * 66];
    __shared__ float Ssl[4][64];

#pragma unroll
    for (int cb = 0; cb < 4; ++cb) {
        float s = csum[cb];
        s += __shfl_xor(s, 16, 64);
        s += __shfl_xor(s, 32, 64);
        if (gq == 0) Ssl[w][cb * 16 + lr] = s;
    }

    for (int ww = 0; ww < 4; ++ww) {
        if (w == ww) {
#pragma unroll
            for (int i = 0; i < 4; ++i)
#pragma unroll
                for (int j = 0; j < 4; ++j)
#pragma unroll
                    for (int q = 0; q < 4; ++q) {
                        const int d = i * 16 + gq * 4 + q;
                        const int e = j * 16 + lr;
                        if (ww == 0) Gl[d * 66 + e] = acc[i][j][q];
                        else         Gl[d * 66 + e] += acc[i][j][q];
                    }
        }
        __syncthreads();
    }

#pragma unroll
    for (int i = 0; i < 16; ++i) {
        const int idx = i * 256 + t;
        const int d = idx >> 6, e = idx & 63;
        Gpart[(size_t)bid * 4096 + idx] = Gl[d * 66 + e];
    }
    if (t < 64)
        Spart[(size_t)bid * 64 + t] = ((Ssl[0][t] + Ssl[1][t]) + (Ssl[2][t] + Ssl[3][t]));
}

// ---------------------------------------------------------------------------
// Kernel 2: reduce 128 partials/group (round-3 proven, verbatim).
// ---------------------------------------------------------------------------
__global__ __launch_bounds__(256) void zca_reduce(const float* __restrict__ Gpart,
                                                  const float* __restrict__ Spart,
                                                  float* __restrict__ Gsum,
                                                  float* __restrict__ Ssub) {
    const int g = blockIdx.x >> 4, eb = blockIdx.x & 15;
    const int t = threadIdx.x;
    const float* p = Gpart + (size_t)g * 128 * 4096 + eb * 256 + t;
    float a0 = 0.f, a1 = 0.f, a2 = 0.f, a3 = 0.f;
    for (int q = 0; q < 128; q += 4) {
        a0 += p[(size_t)(q + 0) * 4096];
        a1 += p[(size_t)(q + 1) * 4096];
        a2 += p[(size_t)(q + 2) * 4096];
        a3 += p[(size_t)(q + 3) * 4096];
    }
    Gsum[(size_t)g * 4096 + eb * 256 + t] = (a0 + a1) + (a2 + a3);

    if (t < 64) {
        float s = 0.f;
        for (int q = 0; q < 8; ++q)
            s += Spart[(size_t)(g * 128 + eb * 8 + q) * 64 + t];
        Ssub[(size_t)(g * 16 + eb) * 64 + t] = s;
    }
}

// ---------------------------------------------------------------------------
// Kernel 3 (round-3 proven): Newton-Schulz. Epilogue now writes bf16 wm
// ROW-major [d][e] (weight folded) for MFMA A-frags, + folded bias.
// ---------------------------------------------------------------------------
__global__ __launch_bounds__(256) void zca_newton(const float* __restrict__ Gsum,
                                                  const float* __restrict__ Ssub,
                                                  const float* __restrict__ weight,
                                                  const float* __restrict__ bias,
                                                  short* __restrict__ wmB,
                                                  float* __restrict__ betaOut) {
    const int g = blockIdx.x;
    const int t = threadIdx.x;
    const int v = t >> 4;
    const int u = t & 15;

    __shared__ float Pm[64 * 65];
    __shared__ float Sn[64 * 65];
    __shared__ float Ta[64 * 65];
    __shared__ float meanS[64];
    __shared__ float scal[2];

    if (t < 64) {
        float s = 0.f;
        for (int eb = 0; eb < 16; ++eb) s += Ssub[(size_t)(g * 16 + eb) * 64 + t];
        meanS[t] = s * (1.0f / MT);
    }
    __syncthreads();

#pragma unroll
    for (int i = 0; i < 16; ++i) {
        int idx = i * 256 + t;
        int d = idx >> 6, e = idx & 63;
        float sig = Gsum[(size_t)g * 4096 + idx] * (1.0f / MT)
                    - meanS[d] * meanS[e] + (d == e ? EPSV : 0.f);
        Sn[d * 65 + e] = sig;
    }
    __syncthreads();

    if (t < 64) {
        float tr = Sn[t * 65 + t];
        for (int off = 32; off > 0; off >>= 1) tr += __shfl_down(tr, off, 64);
        if (t == 0) {
            scal[0] = 1.0f / tr;
            scal[1] = sqrtf(1.0f / tr);
        }
    }
    __syncthreads();
    const float rTr = scal[0];

#pragma unroll
    for (int i = 0; i < 16; ++i) {
        int idx = i * 256 + t;
        int d = idx >> 6, e = idx & 63;
        Sn[d * 65 + e] *= rTr;
        Pm[d * 65 + e] = (d == e) ? 1.f : 0.f;
    }
    __syncthreads();

    auto mm = [&](const float* A, const float* Bm, float* r) {
#pragma unroll
        for (int q = 0; q < 16; ++q) r[q] = 0.f;
        for (int k = 0; k < 64; ++k) {
            float a[4], bb[4];
#pragma unroll
            for (int i = 0; i < 4; ++i) a[i] = A[(v + 16 * i) * 65 + k];
#pragma unroll
            for (int j = 0; j < 4; ++j) bb[j] = Bm[k * 65 + (u + 16 * j)];
#pragma unroll
            for (int i = 0; i < 4; ++i)
#pragma unroll
                for (int j = 0; j < 4; ++j) r[i * 4 + j] += a[i] * bb[j];
        }
    };
    auto storeTa = [&](const float* r) {
#pragma unroll
        for (int q = 0; q < 16; ++q)
            Ta[(v + 16 * (q >> 2)) * 65 + (u + 16 * (q & 3))] = r[q];
    };

    for (int it = 0; it < 5; ++it) {
        float r[16];
        mm(Pm, Sn, r);
        storeTa(r);
        __syncthreads();
        mm(Pm, Ta, r);
        __syncthreads();
        storeTa(r);
        __syncthreads();
        mm(Pm, Ta, r);
        __syncthreads();
#pragma unroll
        for (int q = 0; q < 16; ++q) {
            int rr = v + 16 * (q >> 2);
            int cc = u + 16 * (q & 3);
            Pm[rr * 65 + cc] = 1.5f * Pm[rr * 65 + cc] - 0.5f * r[q];
        }
        __syncthreads();
    }

    // Epilogue: wm = P*sqrt(rTr)*weight -> bf16 ROW-major [d][e]; folded bias.
    const float srTr = scal[1];
#pragma unroll
    for (int i = 0; i < 16; ++i) {
        int idx = i * 256 + t;
        int d = idx >> 6, e = idx & 63;
        float wv = weight[g * NCC + d];
        wmB[(size_t)g * 4096 + d * 64 + e] = (short)f2bf(Pm[d * 65 + e] * srTr * wv);
    }
    if (t < 64) {
        int d = t;
        float s = 0.f;
        for (int e = 0; e < 64; ++e) s += Pm[d * 65 + e] * meanS[e];
        betaOut[g * NCC + d] = bias[g * NCC + d] - weight[g * NCC + d] * srTr * s;
    }
}

// ---------------------------------------------------------------------------
// Kernel 4: MFMA apply.  out[d][m] = sum_e wm[d][e] * X[e][m] + beta[d].
// Grid 512 (g*128+b), 4 waves. Per 64m tile: fp32 LDS staging (round-1 proven
// pattern), wave w owns m-block w*16 + lr (= MFMA col). B-frag: per-lane
// strided ds_read_b32 gather over e + cvt_pk. A-frags preloaded from bf16 wm.
// Conventions exactly as validated in zca_stats / guide m89.
// ---------------------------------------------------------------------------
__global__ __launch_bounds__(256) void zca_apply(const float* __restrict__ X,
                                                 const short* __restrict__ wmB,
                                                 const float* __restrict__ beta,
                                                 float* __restrict__ out) {
    const int bg = blockIdx.x;
    const int g  = bg >> 7;
    const int b  = bg & 127;
    const int t  = threadIdx.x;
    const int w  = t >> 6, l = t & 63;
    const int lr = l & 15, gq = l >> 4;

    __shared__ float Xt[64][68];   // [e][m-within-tile], pitch 68

    // A-frags: wa[i][kc] holds wm[16i + lr][kc*32 + gq*8 + j], j=0..7
    s16x8 wa[4][2];
#pragma unroll
    for (int i = 0; i < 4; ++i)
#pragma unroll
        for (int kc = 0; kc < 2; ++kc)
            wa[i][kc] = *reinterpret_cast<const s16x8*>(
                wmB + (size_t)g * 4096 + (16 * i + lr) * 64 + kc * 32 + gq * 8);

    // beta for output rows d = 16i + 4gq + q
    float bq[4][4];
#pragma unroll
    for (int i = 0; i < 4; ++i) {
        float4 bv = *reinterpret_cast<const float4*>(beta + g * NCC + 16 * i + 4 * gq);
        bq[i][0] = bv.x; bq[i][1] = bv.y; bq[i][2] = bv.z; bq[i][3] = bv.w;
    }

    const float* xb = X + ((size_t)b * NCH + (size_t)g * NCC) * SPA;
    float* ob = out + ((size_t)b * NCH + (size_t)g * NCC) * SPA;

    for (int st = 0; st < SPA; st += 64) {
        __syncthreads();
#pragma unroll
        for (int i = 0; i < 4; ++i) {
            int linear = i * 256 + t;
            int ch = linear >> 4;
            int s4 = linear & 15;
            *reinterpret_cast<float4*>(&Xt[ch][s4 * 4]) =
                *reinterpret_cast<const float4*>(xb + (size_t)ch * SPA + st + s4 * 4);
        }
        __syncthreads();

        // B-frags for this wave's m = st + w*16 + lr (col = lr)
        s16x8 bf[2];
#pragma unroll
        for (int kc = 0; kc < 2; ++kc) {
            float v[8];
#pragma unroll
            for (int j = 0; j < 8; ++j)
                v[j] = Xt[kc * 32 + gq * 8 + j][w * 16 + lr];
            bf[kc] = pack8(v);
        }

        f32x4 acc[4];
#pragma unroll
        for (int i = 0; i < 4; ++i) acc[i] = (f32x4){0.f, 0.f, 0.f, 0.f};
#pragma unroll
        for (int i = 0; i < 4; ++i)
#pragma unroll
            for (int kc = 0; kc < 2; ++kc)
                acc[i] = __builtin_amdgcn_mfma_f32_16x16x32_bf16(wa[i][kc], bf[kc], acc[i], 0, 0, 0);

        const int m = st + w * 16 + lr;
#pragma unroll
        for (int i = 0; i < 4; ++i)
#pragma unroll
            for (int q = 0; q < 4; ++q)
                ob[(size_t)(16 * i + 4 * gq + q) * SPA + m] = acc[i][q] + bq[i][q];
    }
}

// ---------------------------------------------------------------------------
extern "C" void kernel_launch(void* const* d_in, const int* in_sizes, int n_in,
                              void* d_out, int out_size, void* d_ws, size_t ws_size,
                              hipStream_t stream) {
    const float* X      = (const float*)d_in[0];
    const float* weight = (const float*)d_in[1];
    const float* bias   = (const float*)d_in[2];
    float* out = (float*)d_out;

    // ws (floats): Gpart[512*4096] | Spart[512*64] | Gsum[4*4096] |
    //              Ssub[4*16*64] | beta[256] | wmB (4*4096 shorts)
    float* ws    = (float*)d_ws;
    float* Gpart = ws;
    float* Spart = Gpart + (size_t)512 * 4096;
    float* Gsum  = Spart + (size_t)512 * 64;
    float* Ssub  = Gsum + (size_t)4 * 4096;
    float* betaW = Ssub + (size_t)4 * 16 * 64;
    short* wmB   = (short*)(betaW + 256);

    zca_stats <<<dim3(512), dim3(256), 0, stream>>>(X, Gpart, Spart);
    zca_reduce<<<dim3(64),  dim3(256), 0, stream>>>(Gpart, Spart, Gsum, Ssub);
    zca_newton<<<dim3(4),   dim3(256), 0, stream>>>(Gsum, Ssub, weight, bias, wmB, betaW);
    zca_apply <<<dim3(512), dim3(256), 0, stream>>>(X, wmB, betaW, out);
}